// Round 5
// baseline (84.770 us; speedup 1.0000x reference)
//
#include <hip/hip_runtime.h>
#include <hip/hip_cooperative_groups.h>
#include <math.h>

namespace cg = cooperative_groups;

#define H    1024
#define NH   16
#define HD   128
#define ID   2048
#define EPS  1e-6f
#define NBLK 256
#define NTHR 1024

// result in lane 0
__device__ __forceinline__ float waveReduceSum(float v) {
#pragma unroll
    for (int off = 32; off > 0; off >>= 1) v += __shfl_down(v, off, 64);
    return v;
}
// result in all lanes
__device__ __forceinline__ float waveReduceSumAll(float v) {
#pragma unroll
    for (int off = 1; off < 64; off <<= 1) v += __shfl_xor(v, off, 64);
    return v;
}

// One cooperative kernel: 256 blocks x 1024 threads (16 waves/CU = 4/SIMD).
// Phase 1: qkv/z/a matvec (2 rows/wave) + conv copy. W_out rows and state
// slice are preloaded into registers BEFORE phase 1 so their memory traffic
// overlaps the matvec. Phase 2: state update + per-slice readout partials.
// Phase 3: RMSNorm+gate (recomputed per block) + W_out dot from registers.
__global__ __launch_bounds__(NTHR, 4) void fused_qwen_linattn(
    const float* __restrict__ x,
    const float* __restrict__ state_in,
    const float* __restrict__ conv,
    const float* __restrict__ Wqkv,
    const float* __restrict__ Wz,
    const float* __restrict__ Wa,
    const float* __restrict__ normw,
    const float* __restrict__ Wout,
    float* __restrict__ out,
    float* __restrict__ state_out,
    float* __restrict__ conv_out,
    float* __restrict__ ws_qkv,    // [6144] q|k|v
    float* __restrict__ ws_zsig,   // [2048] z*sigmoid(z)
    float* __restrict__ ws_decay,  // [16]
    float* __restrict__ ws_ypart)  // [16][16][128]
{
    cg::grid_group grid = cg::this_grid();
    const int b    = blockIdx.x;
    const int t    = threadIdx.x;
    const int wave = t >> 6;
    const int lane = t & 63;

    __shared__ float4 smem4[512];   // 8 KB: phase2 part[8][128] (first 1024 f) / phase3 gated[2048]
    __shared__ float red[16];
    float* smem = (float*)smem4;

    // ---- register preloads (overlap with phase 1) ----
    // x for the matvec
    const float4* x4 = (const float4*)x;
    float4 xv[4];
#pragma unroll
    for (int i = 0; i < 4; ++i) xv[i] = x4[lane + 64 * i];

    // W_out: row wr = 4b + (t>>8), two float4 chunks per thread
    const int wr = (b << 2) + (t >> 8);
    const int wc = t & 255;
    const float4* wrow4 = (const float4*)(Wout + (size_t)wr * ID);
    const float4 w0 = wrow4[wc];
    const float4 w1 = wrow4[wc + 256];

    // state slice for this block: head h = b>>4, slice s = b&15 (8 d-rows)
    const int h  = b >> 4;
    const int s  = b & 15;
    const int sd = t >> 7;            // 0..7
    const int se = t & 127;           // 0..127
    const size_t sidx = (size_t)h * HD * HD + (size_t)(s * 8 + sd) * HD + se;
    const float sv = state_in[sidx];

    // ================= Phase 1: matvec qkv/z/a + conv =================
    {
        const int gw = b * 16 + wave;         // 0..4095
#pragma unroll
        for (int rr = 0; rr < 2; ++rr) {
            const int r = gw * 2 + rr;        // 0..8191
            const float* row = (r < 3 * ID) ? (Wqkv + (size_t)r * H)
                                            : (Wz + (size_t)(r - 3 * ID) * H);
            const float4* row4 = (const float4*)row;
            float acc = 0.f;
#pragma unroll
            for (int i = 0; i < 4; ++i) {
                float4 wv = row4[lane + 64 * i];
                acc += wv.x * xv[i].x + wv.y * xv[i].y + wv.z * xv[i].z + wv.w * xv[i].w;
            }
            acc = waveReduceSum(acc);
            if (lane == 0) {
                if (r < 3 * ID) ws_qkv[r] = acc;
                else {
                    const float sig = 1.f / (1.f + expf(-acc));
                    ws_zsig[r - 3 * ID] = acc * sig;
                }
            }
        }
        // 16 W_a rows on waves gw=0..15 (block 0)
        if (gw < NH) {
            const float4* row4 = (const float4*)(Wa + (size_t)gw * H);
            float acc = 0.f;
#pragma unroll
            for (int i = 0; i < 4; ++i) {
                float4 wv = row4[lane + 64 * i];
                acc += wv.x * xv[i].x + wv.y * xv[i].y + wv.z * xv[i].z + wv.w * xv[i].w;
            }
            acc = waveReduceSum(acc);
            if (lane == 0) ws_decay[gw] = 1.f / (1.f + expf(-acc));
        }
        // conv passthrough: 4608 float4, 18 per block
        if (t < 18) {
            const int i = b * 18 + t;
            ((float4*)conv_out)[i] = ((const float4*)conv)[i];
        }
    }

    grid.sync();

    // ========== Phase 2: state update + readout partials ==========
    {
        const float decay = ws_decay[h];
        const int dfull = s * 8 + sd;
        const float qd = ws_qkv[h * HD + dfull];
        const float kd = ws_qkv[ID + h * HD + dfull];
        const float ve = ws_qkv[2 * ID + h * HD + se];
        const float sn = sv * decay + kd * ve;
        state_out[sidx] = sn;
        smem[sd * HD + se] = qd * sn;   // part[8][128]
    }
    __syncthreads();
    if (t < HD) {
        float y = 0.f;
#pragma unroll
        for (int d2 = 0; d2 < 8; ++d2) y += smem[d2 * HD + t];
        ws_ypart[(h * 16 + s) * HD + t] = y;
    }

    grid.sync();

    // ========== Phase 3: RMSNorm + gate into LDS, then W_out dot from regs ==========
    {
        // wave w handles head w; each lane 2 consecutive e's
        const int h2 = wave;
        const int e0 = lane * 2;
        float y0 = 0.f, y1 = 0.f;
#pragma unroll 4
        for (int s2 = 0; s2 < 16; ++s2) {
            const float2 yp = *(const float2*)(ws_ypart + (h2 * 16 + s2) * HD + e0);
            y0 += yp.x; y1 += yp.y;
        }
        const float ss = waveReduceSumAll(y0 * y0 + y1 * y1);
        const float scale = rsqrtf(ss * (1.f / HD) + EPS);
        smem[h2 * HD + e0]     = y0 * scale * normw[e0]     * ws_zsig[h2 * HD + e0];
        smem[h2 * HD + e0 + 1] = y1 * scale * normw[e0 + 1] * ws_zsig[h2 * HD + e0 + 1];
    }
    __syncthreads();
    {
        const float4 g0 = smem4[wc];
        const float4 g1 = smem4[wc + 256];
        float acc = w0.x * g0.x + w0.y * g0.y + w0.z * g0.z + w0.w * g0.w
                  + w1.x * g1.x + w1.y * g1.y + w1.z * g1.z + w1.w * g1.w;
        acc = waveReduceSum(acc);
        if (lane == 0) red[wave] = acc;
    }
    __syncthreads();
    if (t < 4) out[(b << 2) + t] = red[4 * t] + red[4 * t + 1] + red[4 * t + 2] + red[4 * t + 3];
}

extern "C" void kernel_launch(void* const* d_in, const int* in_sizes, int n_in,
                              void* d_out, int out_size, void* d_ws, size_t ws_size,
                              hipStream_t stream) {
    const float* x     = (const float*)d_in[0];
    const float* state = (const float*)d_in[1];
    const float* conv  = (const float*)d_in[2];
    const float* Wqkv  = (const float*)d_in[3];
    const float* Wz    = (const float*)d_in[4];
    const float* Wa    = (const float*)d_in[5];
    const float* normw = (const float*)d_in[6];
    const float* Wout  = (const float*)d_in[7];

    float* out       = (float*)d_out;                    // [1024]
    float* new_state = out + H;                          // [16*128*128]
    float* conv_out  = new_state + (size_t)NH * HD * HD; // [18432]

    float* ws       = (float*)d_ws;
    float* ws_qkv   = ws;               // 6144
    float* ws_zsig  = ws + 6144;        // 2048
    float* ws_decay = ws + 8192;        // 16
    float* ws_ypart = ws + 8208;        // 16*16*128 = 32768

    void* args[] = {
        (void*)&x, (void*)&state, (void*)&conv, (void*)&Wqkv, (void*)&Wz,
        (void*)&Wa, (void*)&normw, (void*)&Wout, (void*)&out, (void*)&new_state,
        (void*)&conv_out, (void*)&ws_qkv, (void*)&ws_zsig, (void*)&ws_decay,
        (void*)&ws_ypart
    };
    hipLaunchCooperativeKernel((void*)fused_qwen_linattn,
                               dim3(NBLK), dim3(NTHR), args, 0, stream);
}

// Round 6
// 21.466 us; speedup vs baseline: 3.9491x; 3.9491x over previous
//
#include <hip/hip_runtime.h>
#include <math.h>

#define H    1024
#define NH   16
#define HD   128
#define ID   2048                 // NH*HD
#define NROWS_A (3*ID + ID + NH)  // 6144 qkv + 2048 z + 16 a = 8208
#define MATVEC_BLOCKS (NROWS_A / 4)   // 2052
#define CONV_FLOATS (3 * ID * 3)      // 18432 floats = 4608 float4
#define CONV_BLOCKS (CONV_FLOATS / 4 / 256)  // 18
#define EPS 1e-6f
#define SPLIT 4                   // W_out row-split blocks per head
#define K2_BLOCKS (NH * SPLIT)    // 64

__device__ __forceinline__ float waveReduceSum(float v) {
#pragma unroll
    for (int off = 32; off > 0; off >>= 1) v += __shfl_down(v, off, 64);
    return v;
}

// Kernel 1: fused matvec of x against W_qkv (6144 rows), W_z (2048), W_a (16),
// plus conv passthrough and out[]-zeroing in trailing blocks.
// One wave per row; z rows store z*sigmoid(z); a rows store sigmoid(a).
__global__ __launch_bounds__(256) void matvec_qkvza(
    const float* __restrict__ x,
    const float* __restrict__ Wqkv,
    const float* __restrict__ Wz,
    const float* __restrict__ Wa,
    const float* __restrict__ conv,
    float* __restrict__ conv_out,
    float* __restrict__ out,       // zeroed here (K2 atomicAdds into it)
    float* __restrict__ ws_qkv,    // [6144] q|k|v
    float* __restrict__ ws_zsig,   // [2048] z*sigmoid(z)
    float* __restrict__ ws_decay)  // [16] sigmoid(a)
{
    if (blockIdx.x >= MATVEC_BLOCKS) {
        const int cb = blockIdx.x - MATVEC_BLOCKS;
        const int i = cb * 256 + threadIdx.x;
        ((float4*)conv_out)[i] = ((const float4*)conv)[i];
        if (cb == 0) {   // zero out[1024] = 256 float4
            float4 z4 = {0.f, 0.f, 0.f, 0.f};
            ((float4*)out)[threadIdx.x] = z4;
        }
        return;
    }

    const int wave = threadIdx.x >> 6;
    const int lane = threadIdx.x & 63;
    const int r = blockIdx.x * 4 + wave;

    const float* row;
    if (r < 3 * ID)           row = Wqkv + (size_t)r * H;
    else if (r < 3 * ID + ID) row = Wz   + (size_t)(r - 3 * ID) * H;
    else                      row = Wa   + (size_t)(r - 3 * ID - ID) * H;

    const float4* row4 = (const float4*)row;
    const float4* x4   = (const float4*)x;

    float acc = 0.f;
#pragma unroll
    for (int t = 0; t < 4; ++t) {
        float4 w  = row4[lane + 64 * t];
        float4 xv = x4[lane + 64 * t];
        acc += w.x * xv.x + w.y * xv.y + w.z * xv.z + w.w * xv.w;
    }
    acc = waveReduceSum(acc);
    if (lane == 0) {
        if (r < 3 * ID) {
            ws_qkv[r] = acc;
        } else if (r < 3 * ID + ID) {
            const float sig = 1.f / (1.f + expf(-acc));
            ws_zsig[r - 3 * ID] = acc * sig;
        } else {
            ws_decay[r - 3 * ID - ID] = 1.f / (1.f + expf(-acc));
        }
    }
}

// Kernel 2: per (head h, split p) block of 1024 threads:
//   - read full 128x128 state of head h; sn = s*decay + k (outer) v
//   - waves 4p..4p+3 write their 32 d-rows of new_state (wave-uniform predicate)
//   - y[e] = sum_d q[d]*sn[d,e] via in-wave stride-8 shuffle + LDS across waves
//   - RMSNorm + silu(z)-gate -> gated[128] in LDS
//   - rows r = 256p..256p+255 of W_out partial: 4 threads/row over this head's
//     128 columns; atomicAdd into out[r].
__global__ __launch_bounds__(1024) void head_update_out(
    const float* __restrict__ state_in,
    const float* __restrict__ ws_qkv,
    const float* __restrict__ ws_decay,
    const float* __restrict__ ws_zsig,
    const float* __restrict__ normw,
    const float* __restrict__ Wout,
    float* __restrict__ state_out,
    float* __restrict__ out)
{
    const int h  = blockIdx.x >> 2;
    const int p  = blockIdx.x & 3;
    const int t  = threadIdx.x;
    const int wv = t >> 6;     // wave 0..15
    const int lane = t & 63;
    const int d  = t >> 3;     // 0..127 (d-row this thread reads)
    const int g  = t & 7;      // column-group within d-row

    __shared__ float part[16][HD];   // 8 KB per-wave d-partials
    __shared__ float gated[HD];
    __shared__ float red2[2];

    const float decay = ws_decay[h];
    const float qd = ws_qkv[h * HD + d];
    const float kd = ws_qkv[ID + h * HD + d];

    const float4* sin4 = (const float4*)(state_in  + (size_t)h * HD * HD);
    float4*       sout = (float4*)(state_out + (size_t)h * HD * HD);
    const float4* v4   = (const float4*)(ws_qkv + 2 * ID + h * HD);

    // wave wv covers d-rows 8wv..8wv+7; block p owns d in [32p, 32p+32)
    const bool do_write = (wv >> 2) == p;

    float4 acc[4];
#pragma unroll
    for (int k = 0; k < 4; ++k) {
        const int c = g + 8 * k;        // float4 column 0..31
        const float4 vv = v4[c];
        const float4 sv = sin4[d * 32 + c];
        float4 sn;
        sn.x = sv.x * decay + kd * vv.x;
        sn.y = sv.y * decay + kd * vv.y;
        sn.z = sv.z * decay + kd * vv.z;
        sn.w = sv.w * decay + kd * vv.w;
        if (do_write) sout[d * 32 + c] = sn;
        acc[k].x = qd * sn.x;
        acc[k].y = qd * sn.y;
        acc[k].z = qd * sn.z;
        acc[k].w = qd * sn.w;
    }
    // reduce over the 8 d-rows within this wave (lanes stride 8 share columns)
#pragma unroll
    for (int k = 0; k < 4; ++k) {
#pragma unroll
        for (int off = 8; off < 64; off <<= 1) {
            acc[k].x += __shfl_xor(acc[k].x, off, 64);
            acc[k].y += __shfl_xor(acc[k].y, off, 64);
            acc[k].z += __shfl_xor(acc[k].z, off, 64);
            acc[k].w += __shfl_xor(acc[k].w, off, 64);
        }
    }
    if (lane < 8) {
#pragma unroll
        for (int k = 0; k < 4; ++k)
            ((float4*)part[wv])[lane + 8 * k] = acc[k];
    }
    __syncthreads();

    // y[e] over all 16 waves, then RMSNorm scale
    float y = 0.f;
    if (t < HD) {
#pragma unroll
        for (int w2 = 0; w2 < 16; ++w2) y += part[w2][t];
        float s2 = y * y;
#pragma unroll
        for (int off = 1; off < 64; off <<= 1) s2 += __shfl_xor(s2, off, 64);
        if (lane == 0) red2[t >> 6] = s2;
    }
    __syncthreads();
    if (t < HD) {
        const float scale = rsqrtf((red2[0] + red2[1]) * (1.f / HD) + EPS);
        gated[t] = y * scale * normw[t] * ws_zsig[h * HD + t];
    }
    __syncthreads();

    // W_out partial for rows 256p..256p+255, this head's 128 columns.
    {
        const int r  = p * 256 + (t >> 2);
        const int jq = t & 3;                 // quarter of the 32 float4 cols
        const float4* wrow = (const float4*)(Wout + (size_t)r * ID + h * HD);
        const float4* g4   = (const float4*)gated;
        float a = 0.f;
#pragma unroll
        for (int i = 0; i < 8; ++i) {
            const float4 w4 = wrow[jq * 8 + i];
            const float4 gv = g4[jq * 8 + i];
            a += w4.x * gv.x + w4.y * gv.y + w4.z * gv.z + w4.w * gv.w;
        }
        a += __shfl_xor(a, 1, 64);
        a += __shfl_xor(a, 2, 64);
        if (jq == 0) atomicAdd(&out[r], a);
    }
}

extern "C" void kernel_launch(void* const* d_in, const int* in_sizes, int n_in,
                              void* d_out, int out_size, void* d_ws, size_t ws_size,
                              hipStream_t stream) {
    const float* x     = (const float*)d_in[0];
    const float* state = (const float*)d_in[1];
    const float* conv  = (const float*)d_in[2];
    const float* Wqkv  = (const float*)d_in[3];
    const float* Wz    = (const float*)d_in[4];
    const float* Wa    = (const float*)d_in[5];
    const float* normw = (const float*)d_in[6];
    const float* Wout  = (const float*)d_in[7];

    float* out       = (float*)d_out;                    // [1024]
    float* new_state = out + H;                          // [16*128*128]
    float* conv_out  = new_state + (size_t)NH * HD * HD; // [18432]

    float* ws       = (float*)d_ws;
    float* ws_qkv   = ws;               // 6144
    float* ws_zsig  = ws + 6144;        // 2048
    float* ws_decay = ws + 8192;        // 16

    matvec_qkvza<<<MATVEC_BLOCKS + CONV_BLOCKS, 256, 0, stream>>>(
        x, Wqkv, Wz, Wa, conv, conv_out, out, ws_qkv, ws_zsig, ws_decay);
    head_update_out<<<K2_BLOCKS, 1024, 0, stream>>>(
        state, ws_qkv, ws_decay, ws_zsig, normw, Wout, new_state, out);
}

// Round 7
// 18.077 us; speedup vs baseline: 4.6894x; 1.1875x over previous
//
#include <hip/hip_runtime.h>
#include <math.h>

#define H    1024
#define NH   16
#define HD   128
#define ID   2048                 // NH*HD
#define NROWS_A (3*ID + ID + NH)  // 6144 qkv + 2048 z + 16 a = 8208
#define MATVEC_BLOCKS (NROWS_A / 4)   // 2052
#define CONV_FLOATS (3 * ID * 3)      // 18432 floats = 4608 float4
#define CONV_BLOCKS (CONV_FLOATS / 4 / 256)  // 18
#define EPS 1e-6f

__device__ __forceinline__ float waveReduceSum(float v) {
#pragma unroll
    for (int off = 32; off > 0; off >>= 1) v += __shfl_down(v, off, 64);
    return v;
}
__device__ __forceinline__ float waveReduceSumAll(float v) {
#pragma unroll
    for (int off = 1; off < 64; off <<= 1) v += __shfl_xor(v, off, 64);
    return v;
}

// Kernel 1: fused matvec of x against W_qkv (6144 rows), W_z (2048), W_a (16),
// plus conv passthrough and out[]-zeroing in trailing blocks.
// One wave per row; z rows store z*sigmoid(z); a rows store sigmoid(a).
__global__ __launch_bounds__(256) void matvec_qkvza(
    const float* __restrict__ x,
    const float* __restrict__ Wqkv,
    const float* __restrict__ Wz,
    const float* __restrict__ Wa,
    const float* __restrict__ conv,
    float* __restrict__ conv_out,
    float* __restrict__ out,       // zeroed here (K2 atomicAdds into it)
    float* __restrict__ ws_qkv,    // [6144] q|k|v
    float* __restrict__ ws_zsig,   // [2048] z*sigmoid(z)
    float* __restrict__ ws_decay)  // [16] sigmoid(a)
{
    if (blockIdx.x >= MATVEC_BLOCKS) {
        const int cb = blockIdx.x - MATVEC_BLOCKS;
        const int i = cb * 256 + threadIdx.x;
        ((float4*)conv_out)[i] = ((const float4*)conv)[i];
        if (cb == 0) {   // zero out[1024] = 256 float4
            float4 z4 = {0.f, 0.f, 0.f, 0.f};
            ((float4*)out)[threadIdx.x] = z4;
        }
        return;
    }

    const int wave = threadIdx.x >> 6;
    const int lane = threadIdx.x & 63;
    const int r = blockIdx.x * 4 + wave;

    const float* row;
    if (r < 3 * ID)           row = Wqkv + (size_t)r * H;
    else if (r < 3 * ID + ID) row = Wz   + (size_t)(r - 3 * ID) * H;
    else                      row = Wa   + (size_t)(r - 3 * ID - ID) * H;

    const float4* row4 = (const float4*)row;
    const float4* x4   = (const float4*)x;

    float acc = 0.f;
#pragma unroll
    for (int t = 0; t < 4; ++t) {
        float4 w  = row4[lane + 64 * t];
        float4 xv = x4[lane + 64 * t];
        acc += w.x * xv.x + w.y * xv.y + w.z * xv.z + w.w * xv.w;
    }
    acc = waveReduceSum(acc);
    if (lane == 0) {
        if (r < 3 * ID) {
            ws_qkv[r] = acc;
        } else if (r < 3 * ID + ID) {
            const float sig = 1.f / (1.f + expf(-acc));
            ws_zsig[r - 3 * ID] = acc * sig;
        } else {
            ws_decay[r - 3 * ID - ID] = 1.f / (1.f + expf(-acc));
        }
    }
}

// Kernel 2: 256 blocks = (head h = b>>4, slice s = b&15) x 1024 threads.
// Each block:
//   - reads the FULL 128x128 state of head h (64 KB; 16 blocks/head share it
//     via L2/L3), computes sn = s*decay + k (outer) v for all of it,
//   - wave s writes its 8 d-rows of new_state (one slice, no overlap),
//   - reduces y[e] = sum_d q[d]*sn[d,e] in-block (shuffle + LDS),
//   - RMSNorm + silu(z)-gate -> gated[128],
//   - Wout partial: rows [64s, 64s+64), columns of head h (32 KB, unique),
//     atomicAdd into out.
// Thread layout: c = t&31 (float4 column), dg = t>>5 (0..31, 4 d's each),
// wave wv = t>>6 covers d in [8wv, 8wv+8).
__global__ __launch_bounds__(1024) void state_gate_out(
    const float* __restrict__ state_in,
    const float* __restrict__ ws_qkv,
    const float* __restrict__ ws_decay,
    const float* __restrict__ ws_zsig,
    const float* __restrict__ normw,
    const float* __restrict__ Wout,
    float* __restrict__ state_out,
    float* __restrict__ out)
{
    const int h  = blockIdx.x >> 4;
    const int s  = blockIdx.x & 15;
    const int t  = threadIdx.x;
    const int c  = t & 31;     // float4 column (e = 4c..4c+3)
    const int dg = t >> 5;     // 0..31, covers d = 4dg..4dg+3
    const int wv = t >> 6;     // wave, covers d in [8wv, 8wv+8)
    const int lane = t & 63;

    __shared__ float4 part4[16][32];   // 8 KB: per-wave y partials
    __shared__ float gated[HD];
    __shared__ float red2[2];

    const float decay = ws_decay[h];
    const float4 vv = ((const float4*)(ws_qkv + 2 * ID + h * HD))[c];
    const float4 q4 = ((const float4*)(ws_qkv + h * HD))[dg];
    const float4 k4 = ((const float4*)(ws_qkv + ID + h * HD))[dg];

    const float4* sin4 = (const float4*)(state_in  + (size_t)h * HD * HD);
    float4*       sout = (float4*)(state_out + (size_t)h * HD * HD);

    const bool do_write = (wv == s);   // wave-uniform

    float4 acc = {0.f, 0.f, 0.f, 0.f};
    const float qs[4] = {q4.x, q4.y, q4.z, q4.w};
    const float ks[4] = {k4.x, k4.y, k4.z, k4.w};
#pragma unroll
    for (int i = 0; i < 4; ++i) {
        const int d = dg * 4 + i;
        const float4 sv = sin4[d * 32 + c];
        float4 sn;
        sn.x = sv.x * decay + ks[i] * vv.x;
        sn.y = sv.y * decay + ks[i] * vv.y;
        sn.z = sv.z * decay + ks[i] * vv.z;
        sn.w = sv.w * decay + ks[i] * vv.w;
        if (do_write) sout[d * 32 + c] = sn;
        acc.x += qs[i] * sn.x;
        acc.y += qs[i] * sn.y;
        acc.z += qs[i] * sn.z;
        acc.w += qs[i] * sn.w;
    }
    // combine the wave's two dg halves (lane l <-> l^32 share column c)
    acc.x += __shfl_xor(acc.x, 32, 64);
    acc.y += __shfl_xor(acc.y, 32, 64);
    acc.z += __shfl_xor(acc.z, 32, 64);
    acc.w += __shfl_xor(acc.w, 32, 64);
    if (lane < 32) part4[wv][c] = acc;
    __syncthreads();

    // y[e] over the 16 waves; RMSNorm + gate (threads 0..127)
    const float* partF = (const float*)part4;
    float y = 0.f;
    if (t < HD) {
#pragma unroll
        for (int w2 = 0; w2 < 16; ++w2) y += partF[w2 * HD + t];
        const float s2 = waveReduceSumAll(y * y);
        if (lane == 0) red2[t >> 6] = s2;
    }
    __syncthreads();
    if (t < HD) {
        const float scale = rsqrtf((red2[0] + red2[1]) * (1.f / HD) + EPS);
        gated[t] = y * scale * normw[t] * ws_zsig[h * HD + t];
    }
    __syncthreads();

    // Wout partial: rows r in [64s, 64s+64), columns [128h, 128h+128).
    // 16 threads per row; thread j covers 2 float4 (8 floats).
    {
        const int rl = t >> 4;            // 0..63
        const int j  = t & 15;
        const int r  = s * 64 + rl;
        const float4* wrow = (const float4*)(Wout + (size_t)r * ID + h * HD);
        const float4* g4   = (const float4*)gated;
        const float4 w0 = wrow[j * 2],     w1 = wrow[j * 2 + 1];
        const float4 g0 = g4[j * 2],       g1 = g4[j * 2 + 1];
        float a = w0.x * g0.x + w0.y * g0.y + w0.z * g0.z + w0.w * g0.w
                + w1.x * g1.x + w1.y * g1.y + w1.z * g1.z + w1.w * g1.w;
        a += __shfl_xor(a, 1, 64);
        a += __shfl_xor(a, 2, 64);
        a += __shfl_xor(a, 4, 64);
        a += __shfl_xor(a, 8, 64);
        if (j == 0) atomicAdd(&out[r], a);
    }
}

extern "C" void kernel_launch(void* const* d_in, const int* in_sizes, int n_in,
                              void* d_out, int out_size, void* d_ws, size_t ws_size,
                              hipStream_t stream) {
    const float* x     = (const float*)d_in[0];
    const float* state = (const float*)d_in[1];
    const float* conv  = (const float*)d_in[2];
    const float* Wqkv  = (const float*)d_in[3];
    const float* Wz    = (const float*)d_in[4];
    const float* Wa    = (const float*)d_in[5];
    const float* normw = (const float*)d_in[6];
    const float* Wout  = (const float*)d_in[7];

    float* out       = (float*)d_out;                    // [1024]
    float* new_state = out + H;                          // [16*128*128]
    float* conv_out  = new_state + (size_t)NH * HD * HD; // [18432]

    float* ws       = (float*)d_ws;
    float* ws_qkv   = ws;               // 6144
    float* ws_zsig  = ws + 6144;        // 2048
    float* ws_decay = ws + 8192;        // 16

    matvec_qkvza<<<MATVEC_BLOCKS + CONV_BLOCKS, 256, 0, stream>>>(
        x, Wqkv, Wz, Wa, conv, conv_out, out, ws_qkv, ws_zsig, ws_decay);
    state_gate_out<<<NH * 16, 1024, 0, stream>>>(
        state, ws_qkv, ws_decay, ws_zsig, normw, Wout, new_state, out);
}